// Round 1
// baseline (188.655 us; speedup 1.0000x reference)
//
#include <hip/hip_runtime.h>

// Problem constants (match reference)
#define B_ 8
#define H_ 512
#define W_ 1024
#define HW_ (H_ * W_)
#define G_ 104857
#define N_ (B_ * G_)
#define EPS_ 1e-6f
#define DCOS_ 0.867f
#define DDIFF_ 0.005f
#define DZ_ 1e-5f

// ws layout (byte offsets). Harness re-poisons ws to 0xAA before every timed
// call, so everything below OFF_KEYS is zeroed by one hipMemsetAsync.
#define OFF_BINS 0      // 256 x uint
#define OFF_STATE 1024  // 16 x uint
#define OFF_SUM 1088    // 1 x double (8B aligned)
#define OFF_KEYS 1536   // N_ x uint

#define S_RANK 0
#define S_PREFIX 1
#define S_K 2
#define S_CNTGT 3
#define S_DONE 4

struct F3 { float x, y, z; };
__device__ __forceinline__ F3 f3sub(F3 a, F3 b) { return {a.x - b.x, a.y - b.y, a.z - b.z}; }
__device__ __forceinline__ float f3dot(F3 a, F3 b) { return a.x * b.x + a.y * b.y + a.z * b.z; }
__device__ __forceinline__ F3 f3cross(F3 a, F3 b) {
    return {a.y * b.z - a.z * b.y, a.z * b.x - a.x * b.z, a.x * b.y - a.y * b.x};
}

// loss + valid per triplet; writes orderable key; fused MSB histogram (pass 1)
__global__ void __launch_bounds__(256)
compute_kernel(const float* __restrict__ pred, const float* __restrict__ targ,
               const float* __restrict__ intr,
               const int* __restrict__ p1, const int* __restrict__ p2,
               const int* __restrict__ p3,
               unsigned int* __restrict__ keys, unsigned int* __restrict__ bins)
{
    __shared__ unsigned int lbins[256];
    lbins[threadIdx.x] = 0;
    __syncthreads();

    int b = blockIdx.y;
    int g = blockIdx.x * 256 + threadIdx.x;
    if (g < G_) {
        float f  = intr[b * 9 + 0];   // fx used for both x and y (per reference)
        float u0 = intr[b * 9 + 2];
        float v0 = intr[b * 9 + 5];
        int i1 = p1[b * G_ + g], i2 = p2[b * G_ + g], i3 = p3[b * G_ + g];
        const float* tb = targ + (size_t)b * HW_;
        const float* pb = pred + (size_t)b * HW_;

        auto unproj = [&](const float* dmap, int i) -> F3 {
            float d = dmap[i];
            float u = (float)(i & (W_ - 1));
            float v = (float)(i >> 10);
            F3 P;
            P.x = (u - u0) * d / f;
            P.y = (v - v0) * d / f;
            P.z = d;
            return P;
        };

        F3 G1 = unproj(tb, i1), G2 = unproj(tb, i2), G3 = unproj(tb, i3);
        F3 P1 = unproj(pb, i1), P2 = unproj(pb, i2), P3 = unproj(pb, i3);

        // ---- filter_mask on GT groups ----
        F3 d12 = f3sub(G2, G1), d13 = f3sub(G3, G1), d23 = f3sub(G3, G2);
        float e11 = f3dot(d12, d12), e22 = f3dot(d13, d13), e33 = f3dot(d23, d23);
        float e12 = f3dot(d12, d13), e13 = f3dot(d12, d23), e23 = f3dot(d13, d23);
        float q1 = sqrtf(e11), q2 = sqrtf(e22), q3 = sqrtf(e33);
        int cnt = 0;
        cnt += (fabsf(e11 / (q1 * q1 + EPS_)) > DCOS_) ? 1 : 0;
        cnt += (fabsf(e22 / (q2 * q2 + EPS_)) > DCOS_) ? 1 : 0;
        cnt += (fabsf(e33 / (q3 * q3 + EPS_)) > DCOS_) ? 1 : 0;
        cnt += (fabsf(e12 / (q1 * q2 + EPS_)) > DCOS_) ? 2 : 0;  // symmetric off-diag
        cnt += (fabsf(e13 / (q1 * q3 + EPS_)) > DCOS_) ? 2 : 0;
        cnt += (fabsf(e23 / (q2 * q3 + EPS_)) > DCOS_) ? 2 : 0;
        bool mask_cos = cnt > 3;
        bool mask_pad = (G1.z > DZ_) && (G2.z > DZ_) && (G3.z > DZ_);
        bool mx = (fabsf(d12.x) < DDIFF_) || (fabsf(d13.x) < DDIFF_) || (fabsf(d23.x) < DDIFF_);
        bool my = (fabsf(d12.y) < DDIFF_) || (fabsf(d13.y) < DDIFF_) || (fabsf(d23.y) < DDIFF_);
        bool mz = (fabsf(d12.z) < DDIFF_) || (fabsf(d13.z) < DDIFF_) || (fabsf(d23.z) < DDIFF_);
        bool valid = mask_pad && !((mx && my && mz) || mask_cos);

        // faithful replication: if pred z of point k == 0, set COORDINATE k of
        // all three points to 1e-4 (the reference's broadcast quirk)
        bool c0 = (P1.z == 0.0f), c1 = (P2.z == 0.0f), c2 = (P3.z == 0.0f);
        if (c0) { P1.x = 1e-4f; P2.x = 1e-4f; P3.x = 1e-4f; }
        if (c1) { P1.y = 1e-4f; P2.y = 1e-4f; P3.y = 1e-4f; }
        if (c2) { P1.z = 1e-4f; P2.z = 1e-4f; P3.z = 1e-4f; }

        auto vnormal = [](F3 A, F3 Bp, F3 C) -> F3 {
            F3 a = f3sub(Bp, A), c = f3sub(C, A);
            F3 n = f3cross(a, c);
            float nn = sqrtf(f3dot(n, n));
            nn = nn + ((nn == 0.0f) ? EPS_ : 0.0f);
            return F3{n.x / nn, n.y / nn, n.z / nn};
        };
        F3 ng = vnormal(G1, G2, G3);
        F3 npd = vnormal(P1, P2, P3);
        float loss = fabsf(ng.x - npd.x) + fabsf(ng.y - npd.y) + fabsf(ng.z - npd.z);

        // loss >= 0 -> float bits are order-preserving as uint
        unsigned int key = valid ? __float_as_uint(loss) : 0xFFFFFFFFu;
        keys[(size_t)b * G_ + g] = key;
        if (valid) atomicAdd(&lbins[key >> 24], 1u);
    }
    __syncthreads();
    unsigned int c = lbins[threadIdx.x];
    if (c) atomicAdd(&bins[threadIdx.x], c);
}

// single-block: scan 256 bins, pick bin holding rank, update prefix+rank, zero bins
__global__ void __launch_bounds__(256)
scan_kernel(unsigned int* __restrict__ bins, unsigned int* __restrict__ state, int pass)
{
    __shared__ unsigned int s[256];
    int t = threadIdx.x;
    s[t] = bins[t];
    __syncthreads();
    for (int off = 1; off < 256; off <<= 1) {
        unsigned int add = (t >= off) ? s[t - off] : 0u;
        __syncthreads();
        s[t] += add;
        __syncthreads();
    }
    unsigned int total = s[255];  // pass 0: total == n (valid count)
    unsigned int r = (pass == 0) ? (total / 4) : state[S_RANK];
    if (pass == 0 && t == 0) state[S_K] = total - total / 4;
    __syncthreads();  // all reads of state done before winner writes
    unsigned int csum = s[t];
    unsigned int cprev = (t == 0) ? 0u : s[t - 1];
    if (csum > r && cprev <= r) {  // unique winner (if total>r; n=0 -> no winner, safe)
        state[S_PREFIX] = (state[S_PREFIX] << 8) | (unsigned int)t;
        state[S_RANK] = r - cprev;
    }
    bins[t] = 0;  // ready for next pass
}

__global__ void __launch_bounds__(256)
hist_kernel(const unsigned int* __restrict__ keys, unsigned int* __restrict__ bins,
            const unsigned int* __restrict__ state, int shiftHigh, int shiftBin)
{
    __shared__ unsigned int lbins[256];
    lbins[threadIdx.x] = 0;
    __syncthreads();
    unsigned int prefix = state[S_PREFIX];
    int stride = gridDim.x * 256;
    for (int i = blockIdx.x * 256 + threadIdx.x; i < N_; i += stride) {
        unsigned int k = keys[i];
        if (k != 0xFFFFFFFFu && (k >> shiftHigh) == prefix)
            atomicAdd(&lbins[(k >> shiftBin) & 0xFFu], 1u);
    }
    __syncthreads();
    unsigned int c = lbins[threadIdx.x];
    if (c) atomicAdd(&bins[threadIdx.x], c);
}

// sum of values strictly above threshold + count; last block finalizes
__global__ void __launch_bounds__(256)
sum_kernel(const unsigned int* __restrict__ keys, unsigned int* __restrict__ state,
           double* __restrict__ sumbuf, float* __restrict__ out, int nblocks)
{
    unsigned int tkey = state[S_PREFIX];  // full 32-bit key at rank n//4
    double lsum = 0.0;
    unsigned int lcnt = 0;
    int stride = gridDim.x * 256;
    for (int i = blockIdx.x * 256 + threadIdx.x; i < N_; i += stride) {
        unsigned int k = keys[i];
        if (k != 0xFFFFFFFFu && k > tkey) {
            lsum += (double)__uint_as_float(k);
            lcnt++;
        }
    }
    for (int off = 32; off > 0; off >>= 1) {
        lsum += __shfl_down(lsum, off, 64);
        lcnt += __shfl_down(lcnt, off, 64);
    }
    __shared__ double wsum[4];
    __shared__ unsigned int wcnt[4];
    int lane = threadIdx.x & 63, wv = threadIdx.x >> 6;
    if (lane == 0) { wsum[wv] = lsum; wcnt[wv] = lcnt; }
    __syncthreads();
    if (threadIdx.x == 0) {
        double bs = wsum[0] + wsum[1] + wsum[2] + wsum[3];
        unsigned int bc = wcnt[0] + wcnt[1] + wcnt[2] + wcnt[3];
        atomicAdd(sumbuf, bs);
        atomicAdd(&state[S_CNTGT], bc);
        __threadfence();
        unsigned int done = atomicAdd(&state[S_DONE], 1u);
        if (done == (unsigned int)(nblocks - 1)) {
            double s2 = atomicAdd(sumbuf, 0.0);                 // coherent read
            unsigned int cg = atomicAdd(&state[S_CNTGT], 0u);   // coherent read
            unsigned int K = state[S_K];
            float tv = __uint_as_float(tkey);
            // kept = K largest valid: all > t, plus (K - cnt_gt) copies of t
            double res = s2 + (double)(K - cg) * (double)tv;
            unsigned int denom = (K > 0u) ? K : 1u;
            out[0] = (float)(res / (double)denom);
        }
    }
}

extern "C" void kernel_launch(void* const* d_in, const int* in_sizes, int n_in,
                              void* d_out, int out_size, void* d_ws, size_t ws_size,
                              hipStream_t stream)
{
    const float* pred = (const float*)d_in[0];
    const float* targ = (const float*)d_in[1];
    // d_in[2] = mask: unused by the forward pass (only used in index sampling)
    const float* intr = (const float*)d_in[3];
    const int* p1 = (const int*)d_in[4];
    const int* p2 = (const int*)d_in[5];
    const int* p3 = (const int*)d_in[6];
    float* out = (float*)d_out;

    unsigned char* ws = (unsigned char*)d_ws;
    unsigned int* bins = (unsigned int*)(ws + OFF_BINS);
    unsigned int* state = (unsigned int*)(ws + OFF_STATE);
    double* sumbuf = (double*)(ws + OFF_SUM);
    unsigned int* keys = (unsigned int*)(ws + OFF_KEYS);

    // zero bins/state/sum (ws is poisoned 0xAA before every timed call)
    hipMemsetAsync(d_ws, 0, OFF_KEYS, stream);

    dim3 cgrid((G_ + 255) / 256, B_);
    compute_kernel<<<cgrid, 256, 0, stream>>>(pred, targ, intr, p1, p2, p3, keys, bins);
    scan_kernel<<<1, 256, 0, stream>>>(bins, state, 0);

    const int hblocks = 512;
    hist_kernel<<<hblocks, 256, 0, stream>>>(keys, bins, state, 24, 16);
    scan_kernel<<<1, 256, 0, stream>>>(bins, state, 1);
    hist_kernel<<<hblocks, 256, 0, stream>>>(keys, bins, state, 16, 8);
    scan_kernel<<<1, 256, 0, stream>>>(bins, state, 2);
    hist_kernel<<<hblocks, 256, 0, stream>>>(keys, bins, state, 8, 0);
    scan_kernel<<<1, 256, 0, stream>>>(bins, state, 3);

    const int sblocks = 512;
    sum_kernel<<<sblocks, 256, 0, stream>>>(keys, state, sumbuf, out, sblocks);
}